// Round 5
// baseline (212.663 us; speedup 1.0000x reference)
//
#include <hip/hip_runtime.h>
#include <cstdint>

#define T_TOK 16384
#define H 1024
#define F 256
#define D 3
#define DF 768

typedef unsigned short u16;
typedef __attribute__((ext_vector_type(8))) short short8;
typedef __attribute__((ext_vector_type(4))) float floatx4;

__device__ __forceinline__ u16 f2bf(float f) {
  unsigned u = __float_as_uint(f);
  u += 0x7fff + ((u >> 16) & 1);   // round-to-nearest-even
  return (u16)(u >> 16);
}
__device__ __forceinline__ float bf2f(u16 s) {
  return __uint_as_float(((unsigned)s) << 16);
}

__device__ __forceinline__ void gload_lds16(const void* g, void* l) {
  __builtin_amdgcn_global_load_lds(
      reinterpret_cast<const __attribute__((address_space(1))) void*>(
          reinterpret_cast<uintptr_t>(g)),
      reinterpret_cast<__attribute__((address_space(3))) void*>(
          reinterpret_cast<uintptr_t>(l)),
      16, 0, 0);
}

#define FENCE() asm volatile("" ::: "memory")
#define BARX() do { FENCE(); __builtin_amdgcn_s_barrier(); FENCE(); } while (0)
#define LGKM0() do { asm volatile("s_waitcnt lgkmcnt(0)" ::: "memory"); \
    __builtin_amdgcn_sched_barrier(0); } while (0)
#define VMC(n) asm volatile("s_waitcnt vmcnt(" #n ")" ::: "memory")

__device__ __forceinline__ float block_reduce_256(float v, float* red, int tid) {
  #pragma unroll
  for (int o = 32; o > 0; o >>= 1) v += __shfl_xor(v, o);
  __syncthreads();
  if ((tid & 63) == 0) red[tid >> 6] = v;
  __syncthreads();
  return red[0] + red[1] + red[2] + red[3];
}

// ---------------- prep kernels ----------------

__global__ __launch_bounds__(256)
void prep_elem(const float* __restrict__ W1, const float* __restrict__ lng,
               u16* __restrict__ W1p, const float* __restrict__ W2,
               u16* __restrict__ W2r)
{
  int idx = blockIdx.x * 256 + threadIdx.x;
  int stride = gridDim.x * 256;
  for (int i = idx; i < D * F * H; i += stride) {
    int h = i & (H - 1);
    int d = i / (F * H);
    W1p[i] = f2bf(W1[i] * lng[d * H + h]);
  }
  for (int i = idx; i < H * DF; i += stride) {
    int k = i % DF;           // d*F+f
    int hh = i / DF;
    int d = k >> 8;
    int f = k & (F - 1);
    W2r[i] = f2bf(W2[((size_t)d * H + hh) * F + f]);
  }
}

__global__ __launch_bounds__(256)
void prep_dots(const float* __restrict__ W1, const float* __restrict__ lnb,
               const float* __restrict__ b1, const float* __restrict__ W2,
               const float* __restrict__ gv, const float* __restrict__ b2,
               const float* __restrict__ gb, float* __restrict__ b1p,
               float* __restrict__ wg, float* __restrict__ cg)
{
  __shared__ float red[4];
  int d = blockIdx.x >> 8;
  int f = blockIdx.x & 255;
  int tid = threadIdx.x;
  float s1 = 0.f, s2 = 0.f, s3 = 0.f;
  for (int h = tid; h < H; h += 256) {
    float w1v = W1[((size_t)d * F + f) * H + h];
    float gvv = gv[d * H + h];
    s1 += lnb[d * H + h] * w1v;
    s2 += W2[((size_t)d * H + h) * F + f] * gvv;
    if (f == 0) s3 += b2[d * H + h] * gvv;
  }
  float S1 = block_reduce_256(s1, red, tid);
  float S2 = block_reduce_256(s2, red, tid);
  if (tid == 0) {
    b1p[d * F + f] = b1[d * F + f] + S1;
    wg[d * F + f] = S2;
  }
  if (f == 0) {
    float S3 = block_reduce_256(s3, red, tid);
    if (tid == 0) cg[d] = gb[d] + S3;
  }
}

// ---------------- LayerNorm stats + x·gu dots ----------------
__global__ __launch_bounds__(256)
void ln_xu_kernel(const float* __restrict__ x, const float* __restrict__ gu,
                  u16* __restrict__ xn, float* __restrict__ xu)
{
  int t = blockIdx.x;
  int tid = threadIdx.x;
  const float4 xv = *reinterpret_cast<const float4*>(x + (size_t)t * H + tid * 4);
  const float4 g0 = *reinterpret_cast<const float4*>(gu + tid * 4);
  const float4 g1 = *reinterpret_cast<const float4*>(gu + H + tid * 4);
  const float4 g2 = *reinterpret_cast<const float4*>(gu + 2 * H + tid * 4);
  float s  = xv.x + xv.y + xv.z + xv.w;
  float sq = xv.x * xv.x + xv.y * xv.y + xv.z * xv.z + xv.w * xv.w;
  float d0 = xv.x * g0.x + xv.y * g0.y + xv.z * g0.z + xv.w * g0.w;
  float d1 = xv.x * g1.x + xv.y * g1.y + xv.z * g1.z + xv.w * g1.w;
  float d2 = xv.x * g2.x + xv.y * g2.y + xv.z * g2.z + xv.w * g2.w;
  #pragma unroll
  for (int o = 32; o > 0; o >>= 1) {
    s  += __shfl_xor(s, o);  sq += __shfl_xor(sq, o);
    d0 += __shfl_xor(d0, o); d1 += __shfl_xor(d1, o); d2 += __shfl_xor(d2, o);
  }
  __shared__ float red[4][5];
  int w = tid >> 6;
  if ((tid & 63) == 0) {
    red[w][0] = s; red[w][1] = sq; red[w][2] = d0; red[w][3] = d1; red[w][4] = d2;
  }
  __syncthreads();
  float S  = red[0][0] + red[1][0] + red[2][0] + red[3][0];
  float SQ = red[0][1] + red[1][1] + red[2][1] + red[3][1];
  float mu = S * (1.0f / H);
  float var = (SQ - (float)H * mu * mu) * (1.0f / (H - 1));
  float rs = 1.0f / (sqrtf(fmaxf(var, 0.0f)) + 1e-6f);
  ushort4 o4;
  o4.x = f2bf((xv.x - mu) * rs);
  o4.y = f2bf((xv.y - mu) * rs);
  o4.z = f2bf((xv.z - mu) * rs);
  o4.w = f2bf((xv.w - mu) * rs);
  *reinterpret_cast<ushort4*>(xn + (size_t)t * H + tid * 4) = o4;
  if (tid == 0) {
    xu[t]             = red[0][2] + red[1][2] + red[2][2] + red[3][2];
    xu[T_TOK + t]     = red[0][3] + red[1][3] + red[2][3] + red[3][3];
    xu[2 * T_TOK + t] = red[0][4] + red[1][4] + red[2][4] + red[3][4];
  }
}

// ---------------- reg-A 128x256xBK32 GEMM: C = A·B^T ----------------
// A [M][K] bf16 (L3-resident intermediate) loaded DIRECTLY global->regs,
// double-buffered 1 tile ahead (named aA/aB, static indexing). B [N][K]
// staged in LDS: 3-slot ring x 16KB ([256 rows][32 k] bf16), chunk-XOR
// swizzle key=(row^(row>>2))&3 on global source + read (2-way conflicts).
// 8 waves (2m x 4n), wave tile 64x64, acc[4][4]. Per k-tile: stage B(t+2)
// (2 gload_lds), pref A(t+1) (4 b128), VMC, BAR, 4 ds_read_b128, lgkm0,
// 16 MFMA, BAR. vmcnt ledger: VMC(8) tile0, VMC(6) steady, VMC(4)/(0)
// tail — counted, never drained mid-loop. LDS 48KB + <=128 reg (acc in
// AGPR) -> 2 blocks/CU: epilogue HBM burst overlaps the co-resident
// block's MFMA loop.
template <int K, int NLD, int EPI>
__global__ __launch_bounds__(512, 4)
void gemmd(const u16* __restrict__ A, const u16* __restrict__ Bm,
           const float* __restrict__ p0,  // EPI1: b1p  EPI2: x
           const float* __restrict__ p1,  // EPI1: wg   EPI2: gate[3][T]
           const float* __restrict__ p2,  // EPI1: xu   EPI2: b2[3][H]
           const float* __restrict__ p3,  // EPI1: cg   EPI2: unused
           u16* __restrict__ o16,         // EPI1: mid
           float* __restrict__ o32,       // EPI1: gateOut  EPI2: out
           int nBx)
{
  constexpr int NT = K / 32;          // k-tiles
  constexpr int SLOT = 8192;          // u16 per B slot (16KB)
  extern __shared__ u16 LD[];

  const int tid = threadIdx.x, lane = tid & 63, w = tid >> 6;
  const int wm = w >> 2, wn = w & 3, lr = lane & 15, sl = lane >> 4;

  // bijective XCD swizzle (gridDim.x % 8 == 0)
  const int nwg = gridDim.x;
  const int wgs = (blockIdx.x & 7) * (nwg >> 3) + (blockIdx.x >> 3);
  const int bx = wgs % nBx, by = wgs / nBx;
  const int m0 = by * 128, n0 = bx * 256;

  // A direct-load base: rows m0 + wm*64 + mf*16 + lr, k = t*32 + sl*8
  const u16* Aptr = A + (size_t)(m0 + wm * 64 + lr) * K + sl * 8;
  const u16* Bsrc = Bm + (size_t)n0 * K;

  // B staging: chunk c = it*512 + tid; row = c>>2, slot = c&3;
  // source col-group = slot ^ key(row), key = (row ^ (row>>2)) & 3
  const int c0r = tid >> 2, c0s = tid & 3;
  const int c1r = (tid + 512) >> 2, c1s = tid & 3;  // +512 keeps low2 bits
  const int key0 = (c0r ^ (c0r >> 2)) & 3;
  const int key1 = (c1r ^ (c1r >> 2)) & 3;
  const u16* gB0 = Bsrc + (size_t)c0r * K + ((c0s ^ key0) << 3);
  const u16* gB1 = Bsrc + (size_t)c1r * K + ((c1s ^ key1) << 3);
  const int ldst0 = w * 512;          // wave-uniform (+lane*16B implicit)
  const int ldst1 = 4096 + w * 512;

  // B read: row = wn*64 + nf*16 + lr; slot-XOR key per-lane
  const int rkey = (lr ^ (lr >> 2)) & 3;
  const int boff = (wn * 64 + lr) * 32 + ((sl ^ rkey) << 3);

  floatx4 acc[4][4] = {};
  short8 aA[4], aB[4], b[4];

#define STGB(SP, T_) do { \
    gload_lds16(gB0 + (T_) * 32, (SP) + ldst0); \
    gload_lds16(gB1 + (T_) * 32, (SP) + ldst1); \
  } while (0)
#define PREFA(AR, T_) do { \
    _Pragma("unroll") for (int mf_ = 0; mf_ < 4; ++mf_) \
      AR[mf_] = *reinterpret_cast<const short8*>( \
          Aptr + (size_t)mf_ * 16 * K + (T_) * 32); } while (0)
#define LDB(SP) do { const u16* sb_ = (SP) + boff; \
    _Pragma("unroll") for (int nf_ = 0; nf_ < 4; ++nf_) \
      b[nf_] = *reinterpret_cast<const short8*>(sb_ + nf_ * 512); } while (0)
#define MMX(AR) do { __builtin_amdgcn_s_setprio(1); \
    _Pragma("unroll") for (int mf_ = 0; mf_ < 4; ++mf_) \
      _Pragma("unroll") for (int nf_ = 0; nf_ < 4; ++nf_) \
        acc[mf_][nf_] = __builtin_amdgcn_mfma_f32_16x16x32_bf16( \
            AR[mf_], b[nf_], acc[mf_][nf_], 0, 0, 0); \
    __builtin_amdgcn_s_setprio(0); } while (0)

  // prologue: A0 -> aA; B tiles 0,1 -> slots 0,1
  PREFA(aA, 0);
  STGB(LD, 0);
  STGB(LD + SLOT, 1);
  // tile 0 (even, aA): stage B2->slot2, pref A1->aB
  STGB(LD + 2 * SLOT, 2);
  PREFA(aB, 1);
  VMC(8); BARX();
  LDB(LD); LGKM0(); MMX(aA); BARX();

  int s = 1;                          // slot of tile t (t%3)
  #pragma unroll 1
  for (int i = 0; i < (NT - 4) / 2; ++i) {
    const int t = 2 * i + 1;
    {   // odd tile t: uses aB; stage B(t+2); pref A(t+1)->aA
      int s2 = s + 2; if (s2 >= 3) s2 -= 3;
      STGB(LD + s2 * SLOT, t + 2);
      PREFA(aA, t + 1);
      VMC(6); BARX();
      LDB(LD + s * SLOT); LGKM0(); MMX(aB); BARX();
      ++s; if (s == 3) s = 0;
    }
    {   // even tile t+1: uses aA; stage B(t+3); pref A(t+2)->aB
      int s2 = s + 2; if (s2 >= 3) s2 -= 3;
      STGB(LD + s2 * SLOT, t + 3);
      PREFA(aB, t + 2);
      VMC(6); BARX();
      LDB(LD + s * SLOT); LGKM0(); MMX(aA); BARX();
      ++s; if (s == 3) s = 0;
    }
  }
  {   // tile NT-3 (odd, aB): stage B(NT-1); pref A(NT-2)->aA
    int s2 = s + 2; if (s2 >= 3) s2 -= 3;
    STGB(LD + s2 * SLOT, NT - 1);
    PREFA(aA, NT - 2);
    VMC(6); BARX();
    LDB(LD + s * SLOT); LGKM0(); MMX(aB); BARX();
    ++s; if (s == 3) s = 0;
  }
  {   // tile NT-2 (even, aA): pref A(NT-1)->aB
    PREFA(aB, NT - 1);
    VMC(4); BARX();
    LDB(LD + s * SLOT); LGKM0(); MMX(aA); BARX();
    ++s; if (s == 3) s = 0;
  }
  {   // tile NT-1 (odd, aB)
    VMC(0); BARX();
    LDB(LD + s * SLOT); LGKM0(); MMX(aB); BARX();
  }

  // ---- epilogue; C/D frag layout: col=lane&15, row=(lane>>4)*4+i ----
  if constexpr (EPI == 1) {
    // mid = relu(acc + b1p); fused gate: g = sigmoid(Σ mid·wg + xu + cg)
    float b1v[4], wgv[4];
    #pragma unroll
    for (int nf = 0; nf < 4; ++nf) {
      int col = n0 + wn * 64 + nf * 16 + lr;
      b1v[nf] = p0[col];
      wgv[nf] = p1[col];
    }
    float* red = (float*)LD;   // [4 wn][128 rows]
    #pragma unroll
    for (int mf = 0; mf < 4; ++mf)
      #pragma unroll
      for (int i2 = 0; i2 < 4; ++i2) {
        float p = 0.f;
        #pragma unroll
        for (int nf = 0; nf < 4; ++nf)
          p += fmaxf(acc[mf][nf][i2] + b1v[nf], 0.f) * wgv[nf];
        p += __shfl_xor(p, 1); p += __shfl_xor(p, 2);
        p += __shfl_xor(p, 4); p += __shfl_xor(p, 8);
        if (lr == 0) red[wn * 128 + wm * 64 + mf * 16 + sl * 4 + i2] = p;
      }
    __syncthreads();
    const int d = bx;          // block n-tile == domain
    const float cgv = p3[d];
    #pragma unroll
    for (int mf = 0; mf < 4; ++mf)
      #pragma unroll
      for (int i2 = 0; i2 < 4; ++i2) {
        int rl = wm * 64 + mf * 16 + sl * 4 + i2;
        int r = m0 + rl;
        float logit = red[rl] + red[128 + rl] + red[256 + rl] + red[384 + rl]
                    + p2[(size_t)d * T_TOK + r] + cgv;
        float g = 1.f / (1.f + expf(-logit));
        #pragma unroll
        for (int nf = 0; nf < 4; ++nf) {
          int col = n0 + wn * 64 + nf * 16 + lr;
          float v = fmaxf(acc[mf][nf][i2] + b1v[nf], 0.f);
          o16[(size_t)r * NLD + col] = f2bf(v * g);
        }
        if (lr == 0 && wn == 0) o32[(size_t)d * T_TOK + r] = g;
      }
  } else {
    // out = acc + 2x + Σ_d g_d·b2[d]
    float b2v[3][4];
    #pragma unroll
    for (int dd = 0; dd < 3; ++dd)
      #pragma unroll
      for (int nf = 0; nf < 4; ++nf)
        b2v[dd][nf] = p2[dd * H + n0 + wn * 64 + nf * 16 + lr];
    #pragma unroll
    for (int mf = 0; mf < 4; ++mf)
      #pragma unroll
      for (int i2 = 0; i2 < 4; ++i2) {
        int r = m0 + wm * 64 + mf * 16 + sl * 4 + i2;
        float g0 = p1[r], g1 = p1[T_TOK + r], g2 = p1[2 * T_TOK + r];
        const float* xrow = p0 + (size_t)r * H;
        float* orow = o32 + (size_t)r * NLD;
        #pragma unroll
        for (int nf = 0; nf < 4; ++nf) {
          int col = n0 + wn * 64 + nf * 16 + lr;
          orow[col] = acc[mf][nf][i2] + 2.f * xrow[col]
                    + g0 * b2v[0][nf] + g1 * b2v[1][nf] + g2 * b2v[2][nf];
        }
      }
  }
#undef STGB
#undef PREFA
#undef LDB
#undef MMX
}

// ---------------- launch ----------------

extern "C" void kernel_launch(void* const* d_in, const int* in_sizes, int n_in,
                              void* d_out, int out_size, void* d_ws, size_t ws_size,
                              hipStream_t stream) {
  const float* x   = (const float*)d_in[0];
  const float* lng = (const float*)d_in[1];
  const float* lnb = (const float*)d_in[2];
  const float* W1  = (const float*)d_in[3];
  const float* b1  = (const float*)d_in[4];
  const float* W2  = (const float*)d_in[5];
  const float* b2  = (const float*)d_in[6];
  const float* gu  = (const float*)d_in[7];
  const float* gv  = (const float*)d_in[8];
  const float* gb  = (const float*)d_in[9];
  float* out = (float*)d_out;

  char* ws = (char*)d_ws;
  u16* xn   = (u16*)ws;  ws += (size_t)T_TOK * H * 2;     // 32 MB
  u16* mid  = (u16*)ws;  ws += (size_t)T_TOK * DF * 2;    // 24 MB
  u16* W1p  = (u16*)ws;  ws += (size_t)DF * H * 2;
  u16* W2r  = (u16*)ws;  ws += (size_t)H * DF * 2;
  float* b1p  = (float*)ws;  ws += DF * 4;
  float* wg   = (float*)ws;  ws += DF * 4;
  float* cg   = (float*)ws;  ws += 256;
  float* xu   = (float*)ws;  ws += (size_t)D * T_TOK * 4;
  float* gate = (float*)ws;  ws += (size_t)D * T_TOK * 4;
  (void)ws_size; (void)in_sizes; (void)n_in; (void)out_size;

  hipFuncSetAttribute(reinterpret_cast<const void*>(&gemmd<1024, DF, 1>),
                      hipFuncAttributeMaxDynamicSharedMemorySize, 49152);
  hipFuncSetAttribute(reinterpret_cast<const void*>(&gemmd<768, H, 2>),
                      hipFuncAttributeMaxDynamicSharedMemorySize, 49152);

  prep_elem<<<3072, 256, 0, stream>>>(W1, lng, W1p, W2, W2r);
  prep_dots<<<DF, 256, 0, stream>>>(W1, lnb, b1, W2, gv, b2, gb, b1p, wg, cg);
  ln_xu_kernel<<<T_TOK, 256, 0, stream>>>(x, gu, xn, xu);
  // GEMM1: mid[16384x768] = xn[16384x1024] · W1p[768x1024]^T  (+gate)
  gemmd<1024, DF, 1><<<128 * 3, 512, 49152, stream>>>(
      xn, W1p, b1p, wg, xu, cg, mid, gate, 3);
  // GEMM2: out[16384x1024] = mid[16384x768] · W2r[1024x768]^T (+epilogue)
  gemmd<768, H, 2><<<128 * 4, 512, 49152, stream>>>(
      mid, W2r, x, gate, b2, nullptr, nullptr, out, 4);
}

// Round 6
// 132.644 us; speedup vs baseline: 1.6033x; 1.6033x over previous
//
#include <hip/hip_runtime.h>
#include <cstdint>

#define T_TOK 16384
#define H 1024
#define F 256
#define D 3
#define DF 768

typedef unsigned short u16;
typedef __attribute__((ext_vector_type(8))) short short8;
typedef __attribute__((ext_vector_type(4))) float floatx4;

__device__ __forceinline__ u16 f2bf(float f) {
  unsigned u = __float_as_uint(f);
  u += 0x7fff + ((u >> 16) & 1);   // round-to-nearest-even
  return (u16)(u >> 16);
}
__device__ __forceinline__ float bf2f(u16 s) {
  return __uint_as_float(((unsigned)s) << 16);
}

__device__ __forceinline__ void gload_lds16(const void* g, void* l) {
  __builtin_amdgcn_global_load_lds(
      reinterpret_cast<const __attribute__((address_space(1))) void*>(
          reinterpret_cast<uintptr_t>(g)),
      reinterpret_cast<__attribute__((address_space(3))) void*>(
          reinterpret_cast<uintptr_t>(l)),
      16, 0, 0);
}

__device__ __forceinline__ float block_reduce_256(float v, float* red, int tid) {
  #pragma unroll
  for (int o = 32; o > 0; o >>= 1) v += __shfl_xor(v, o);
  __syncthreads();
  if ((tid & 63) == 0) red[tid >> 6] = v;
  __syncthreads();
  return red[0] + red[1] + red[2] + red[3];
}

// ---------------- prep kernels ----------------

__global__ __launch_bounds__(256)
void prep_elem(const float* __restrict__ W1, const float* __restrict__ lng,
               u16* __restrict__ W1p, const float* __restrict__ W2,
               u16* __restrict__ W2r)
{
  int idx = blockIdx.x * 256 + threadIdx.x;
  int stride = gridDim.x * 256;
  for (int i = idx; i < D * F * H; i += stride) {
    int h = i & (H - 1);
    int d = i / (F * H);
    W1p[i] = f2bf(W1[i] * lng[d * H + h]);
  }
  for (int i = idx; i < H * DF; i += stride) {
    int k = i % DF;           // d*F+f
    int hh = i / DF;
    int d = k >> 8;
    int f = k & (F - 1);
    W2r[i] = f2bf(W2[((size_t)d * H + hh) * F + f]);
  }
}

__global__ __launch_bounds__(256)
void prep_dots(const float* __restrict__ W1, const float* __restrict__ lnb,
               const float* __restrict__ b1, const float* __restrict__ W2,
               const float* __restrict__ gv, const float* __restrict__ b2,
               const float* __restrict__ gb, float* __restrict__ b1p,
               float* __restrict__ wg, float* __restrict__ cg)
{
  __shared__ float red[4];
  int d = blockIdx.x >> 8;
  int f = blockIdx.x & 255;
  int tid = threadIdx.x;
  float s1 = 0.f, s2 = 0.f, s3 = 0.f;
  for (int h = tid; h < H; h += 256) {
    float w1v = W1[((size_t)d * F + f) * H + h];
    float gvv = gv[d * H + h];
    s1 += lnb[d * H + h] * w1v;
    s2 += W2[((size_t)d * H + h) * F + f] * gvv;
    if (f == 0) s3 += b2[d * H + h] * gvv;
  }
  float S1 = block_reduce_256(s1, red, tid);
  float S2 = block_reduce_256(s2, red, tid);
  if (tid == 0) {
    b1p[d * F + f] = b1[d * F + f] + S1;
    wg[d * F + f] = S2;
  }
  if (f == 0) {
    float S3 = block_reduce_256(s3, red, tid);
    if (tid == 0) cg[d] = gb[d] + S3;
  }
}

// ---------------- LayerNorm stats + x·gu dots ----------------
__global__ __launch_bounds__(256)
void ln_xu_kernel(const float* __restrict__ x, const float* __restrict__ gu,
                  u16* __restrict__ xn, float* __restrict__ xu)
{
  int t = blockIdx.x;
  int tid = threadIdx.x;
  const float4 xv = *reinterpret_cast<const float4*>(x + (size_t)t * H + tid * 4);
  const float4 g0 = *reinterpret_cast<const float4*>(gu + tid * 4);
  const float4 g1 = *reinterpret_cast<const float4*>(gu + H + tid * 4);
  const float4 g2 = *reinterpret_cast<const float4*>(gu + 2 * H + tid * 4);
  float s  = xv.x + xv.y + xv.z + xv.w;
  float sq = xv.x * xv.x + xv.y * xv.y + xv.z * xv.z + xv.w * xv.w;
  float d0 = xv.x * g0.x + xv.y * g0.y + xv.z * g0.z + xv.w * g0.w;
  float d1 = xv.x * g1.x + xv.y * g1.y + xv.z * g1.z + xv.w * g1.w;
  float d2 = xv.x * g2.x + xv.y * g2.y + xv.z * g2.z + xv.w * g2.w;
  #pragma unroll
  for (int o = 32; o > 0; o >>= 1) {
    s  += __shfl_xor(s, o);  sq += __shfl_xor(sq, o);
    d0 += __shfl_xor(d0, o); d1 += __shfl_xor(d1, o); d2 += __shfl_xor(d2, o);
  }
  __shared__ float red[4][5];
  int w = tid >> 6;
  if ((tid & 63) == 0) {
    red[w][0] = s; red[w][1] = sq; red[w][2] = d0; red[w][3] = d1; red[w][4] = d2;
  }
  __syncthreads();
  float S  = red[0][0] + red[1][0] + red[2][0] + red[3][0];
  float SQ = red[0][1] + red[1][1] + red[2][1] + red[3][1];
  float mu = S * (1.0f / H);
  float var = (SQ - (float)H * mu * mu) * (1.0f / (H - 1));
  float rs = 1.0f / (sqrtf(fmaxf(var, 0.0f)) + 1e-6f);
  ushort4 o4;
  o4.x = f2bf((xv.x - mu) * rs);
  o4.y = f2bf((xv.y - mu) * rs);
  o4.z = f2bf((xv.z - mu) * rs);
  o4.w = f2bf((xv.w - mu) * rs);
  *reinterpret_cast<ushort4*>(xn + (size_t)t * H + tid * 4) = o4;
  if (tid == 0) {
    xu[t]             = red[0][2] + red[1][2] + red[2][2] + red[3][2];
    xu[T_TOK + t]     = red[0][3] + red[1][3] + red[2][3] + red[3][3];
    xu[2 * T_TOK + t] = red[0][4] + red[1][4] + red[2][4] + red[3][4];
  }
}

// ---------------- 2-phase 128x256xBK32 GEMM: C = A·B^T ----------------
// T3-minimum structure (m97/m248-V0): double-buffered LDS, ONE
// __syncthreads() per K-tile, NO manual waitcnt/sched_barrier — compiler
// emits progressive lgkmcnt and the full drain at the barrier; the drain
// stall is filled by the co-resident block (2 blocks/CU: 48KB LDS,
// launch_bounds(512,4)).
// 8 waves (2m x 4n), wave tile 64x64, acc[4][4] 16x16x32 frags.
// Buffer (24KB): A[128][32] @0, B[256][32] @4096 (u16 elems).
// Swizzle (both-sides, rule #21): 16B-chunk cs at row r holds global
// chunk cs^((r>>1)&3); read key=(lr>>1)&3 (invariant across mf/nf since
// frag-row steps are multiples of 16). Bank audit: 2 lanes/bank = free.
// Staging: 3 gload_lds16/thread/tile (A:1, B:2), linear dest.
template <int K, int NLD, int EPI>
__global__ __launch_bounds__(512, 4)
void gemm2p(const u16* __restrict__ A, const u16* __restrict__ Bm,
            const float* __restrict__ p0,  // EPI1: b1p  EPI2: x
            const float* __restrict__ p1,  // EPI1: wg   EPI2: gate[3][T]
            const float* __restrict__ p2,  // EPI1: xu   EPI2: b2[3][H]
            const float* __restrict__ p3,  // EPI1: cg   EPI2: unused
            u16* __restrict__ o16,         // EPI1: mid
            float* __restrict__ o32,       // EPI1: gateOut  EPI2: out
            int nBy)
{
  constexpr int NT = K / 32;          // K-tiles
  constexpr int BUF = 12288;          // u16 elems per buffer (24KB)
  extern __shared__ u16 LD[];

  const int tid = threadIdx.x, lane = tid & 63, w = tid >> 6;
  const int wm = w >> 2, wn = w & 3, lr = lane & 15, sl = lane >> 4;

  // bijective XCD swizzle (gridDim.x % 8 == 0); by fastest -> each XCD
  // chunk shares one B panel (L2-resident weights)
  const int nwg = gridDim.x;
  const int wgs = (blockIdx.x & 7) * (nwg >> 3) + (blockIdx.x >> 3);
  const int by = wgs % nBy, bx = wgs / nBy;
  const int m0 = by * 128, n0 = bx * 256;

  const u16* Asrc = A + (size_t)m0 * K;
  const u16* Bsrc = Bm + (size_t)n0 * K;

  // staging: thread -> (row = tid>>2, chunk cs = tid&3), source chunk
  // pre-swizzled: sc = cs ^ ((row>>1)&3) = (tid&3) ^ ((tid>>3)&3)
  const int sc = (tid & 3) ^ ((tid >> 3) & 3);
  const int srcA  = (tid >> 2) * K + sc * 8;       // A rows 0..127, B rows 0..127
  const int srcB1 = srcA + 128 * K;                // B rows 128..255 (same key)
  const int dstA  = w * 512;                       // wave-uniform dest bases
  const int dstB0 = 4096 + w * 512;
  const int dstB1 = 8192 + w * 512;

  // fragment reads: row = {wm,wn}*64 + frag*16 + lr; key = (lr>>1)&3
  const int key = (lr >> 1) & 3;
  const int rsl = (sl ^ key) << 3;
  const int aoff = (wm * 64 + lr) * 32 + rsl;           // A slab @0
  const int boff = 4096 + (wn * 64 + lr) * 32 + rsl;    // B slab @4096

  floatx4 acc[4][4] = {};
  short8 a[4], b[4];

#define STG(BP, T_) do { int kb_ = (T_) * 32; \
    gload_lds16(Asrc + srcA + kb_, (BP) + dstA); \
    gload_lds16(Bsrc + srcA + kb_, (BP) + dstB0); \
    gload_lds16(Bsrc + srcB1 + kb_, (BP) + dstB1); \
  } while (0)
#define LDAB(BP) do { \
    const u16* sa_ = (BP) + aoff; const u16* sb_ = (BP) + boff; \
    _Pragma("unroll") for (int i_ = 0; i_ < 4; ++i_) { \
      a[i_] = *reinterpret_cast<const short8*>(sa_ + i_ * 512); \
      b[i_] = *reinterpret_cast<const short8*>(sb_ + i_ * 512); } } while (0)
#define MMX() do { \
    _Pragma("unroll") for (int mf_ = 0; mf_ < 4; ++mf_) \
      _Pragma("unroll") for (int nf_ = 0; nf_ < 4; ++nf_) \
        acc[mf_][nf_] = __builtin_amdgcn_mfma_f32_16x16x32_bf16( \
            a[mf_], b[nf_], acc[mf_][nf_], 0, 0, 0); } while (0)

  STG(LD, 0);
  __syncthreads();

  #pragma unroll 1
  for (int t = 0; t < NT - 1; ++t) {
    u16* cur = LD + (t & 1) * BUF;
    u16* nxt = LD + ((t + 1) & 1) * BUF;
    STG(nxt, t + 1);          // async; drained by the syncthreads below
    LDAB(cur);
    MMX();
    __syncthreads();          // compiler: waitcnt vmcnt(0) lgkmcnt(0) + barrier
  }
  LDAB(LD + ((NT - 1) & 1) * BUF);
  MMX();
  __syncthreads();            // LDS free for epilogue

  // ---- epilogue; C/D frag layout: col=lane&15, row=(lane>>4)*4+i ----
  if constexpr (EPI == 1) {
    // mid = relu(acc + b1p); fused gate: g = sigmoid(Σ mid·wg + xu + cg)
    float b1v[4], wgv[4];
    #pragma unroll
    for (int nf = 0; nf < 4; ++nf) {
      int col = n0 + wn * 64 + nf * 16 + lr;
      b1v[nf] = p0[col];
      wgv[nf] = p1[col];
    }
    float* red = (float*)LD;   // [4 wn][128 rows]
    #pragma unroll
    for (int mf = 0; mf < 4; ++mf)
      #pragma unroll
      for (int i2 = 0; i2 < 4; ++i2) {
        float p = 0.f;
        #pragma unroll
        for (int nf = 0; nf < 4; ++nf)
          p += fmaxf(acc[mf][nf][i2] + b1v[nf], 0.f) * wgv[nf];
        p += __shfl_xor(p, 1); p += __shfl_xor(p, 2);
        p += __shfl_xor(p, 4); p += __shfl_xor(p, 8);
        if (lr == 0) red[wn * 128 + wm * 64 + mf * 16 + sl * 4 + i2] = p;
      }
    __syncthreads();
    const int d = bx;          // block n-tile == domain
    const float cgv = p3[d];
    #pragma unroll
    for (int mf = 0; mf < 4; ++mf)
      #pragma unroll
      for (int i2 = 0; i2 < 4; ++i2) {
        int rl = wm * 64 + mf * 16 + sl * 4 + i2;
        int r = m0 + rl;
        float logit = red[rl] + red[128 + rl] + red[256 + rl] + red[384 + rl]
                    + p2[(size_t)d * T_TOK + r] + cgv;
        float g = 1.f / (1.f + expf(-logit));
        #pragma unroll
        for (int nf = 0; nf < 4; ++nf) {
          int col = n0 + wn * 64 + nf * 16 + lr;
          float v = fmaxf(acc[mf][nf][i2] + b1v[nf], 0.f);
          o16[(size_t)r * NLD + col] = f2bf(v * g);
        }
        if (lr == 0 && wn == 0) o32[(size_t)d * T_TOK + r] = g;
      }
  } else {
    // out = acc + 2x + Σ_d g_d·b2[d]
    float b2v[3][4];
    #pragma unroll
    for (int dd = 0; dd < 3; ++dd)
      #pragma unroll
      for (int nf = 0; nf < 4; ++nf)
        b2v[dd][nf] = p2[dd * H + n0 + wn * 64 + nf * 16 + lr];
    #pragma unroll
    for (int mf = 0; mf < 4; ++mf)
      #pragma unroll
      for (int i2 = 0; i2 < 4; ++i2) {
        int r = m0 + wm * 64 + mf * 16 + sl * 4 + i2;
        float g0 = p1[r], g1 = p1[T_TOK + r], g2 = p1[2 * T_TOK + r];
        const float* xrow = p0 + (size_t)r * H;
        float* orow = o32 + (size_t)r * NLD;
        #pragma unroll
        for (int nf = 0; nf < 4; ++nf) {
          int col = n0 + wn * 64 + nf * 16 + lr;
          orow[col] = acc[mf][nf][i2] + 2.f * xrow[col]
                    + g0 * b2v[0][nf] + g1 * b2v[1][nf] + g2 * b2v[2][nf];
        }
      }
  }
#undef STG
#undef LDAB
#undef MMX
}

// ---------------- launch ----------------

extern "C" void kernel_launch(void* const* d_in, const int* in_sizes, int n_in,
                              void* d_out, int out_size, void* d_ws, size_t ws_size,
                              hipStream_t stream) {
  const float* x   = (const float*)d_in[0];
  const float* lng = (const float*)d_in[1];
  const float* lnb = (const float*)d_in[2];
  const float* W1  = (const float*)d_in[3];
  const float* b1  = (const float*)d_in[4];
  const float* W2  = (const float*)d_in[5];
  const float* b2  = (const float*)d_in[6];
  const float* gu  = (const float*)d_in[7];
  const float* gv  = (const float*)d_in[8];
  const float* gb  = (const float*)d_in[9];
  float* out = (float*)d_out;

  char* ws = (char*)d_ws;
  u16* xn   = (u16*)ws;  ws += (size_t)T_TOK * H * 2;     // 32 MB
  u16* mid  = (u16*)ws;  ws += (size_t)T_TOK * DF * 2;    // 24 MB
  u16* W1p  = (u16*)ws;  ws += (size_t)DF * H * 2;
  u16* W2r  = (u16*)ws;  ws += (size_t)H * DF * 2;
  float* b1p  = (float*)ws;  ws += DF * 4;
  float* wg   = (float*)ws;  ws += DF * 4;
  float* cg   = (float*)ws;  ws += 256;
  float* xu   = (float*)ws;  ws += (size_t)D * T_TOK * 4;
  float* gate = (float*)ws;  ws += (size_t)D * T_TOK * 4;
  (void)ws_size; (void)in_sizes; (void)n_in; (void)out_size;

  hipFuncSetAttribute(reinterpret_cast<const void*>(&gemm2p<1024, DF, 1>),
                      hipFuncAttributeMaxDynamicSharedMemorySize, 49152);
  hipFuncSetAttribute(reinterpret_cast<const void*>(&gemm2p<768, H, 2>),
                      hipFuncAttributeMaxDynamicSharedMemorySize, 49152);

  prep_elem<<<3072, 256, 0, stream>>>(W1, lng, W1p, W2, W2r);
  prep_dots<<<DF, 256, 0, stream>>>(W1, lnb, b1, W2, gv, b2, gb, b1p, wg, cg);
  ln_xu_kernel<<<T_TOK, 256, 0, stream>>>(x, gu, xn, xu);
  // GEMM1: mid[16384x768] = xn[16384x1024] · W1p[768x1024]^T  (+gate)
  gemm2p<1024, DF, 1><<<128 * 3, 512, 49152, stream>>>(
      xn, W1p, b1p, wg, xu, cg, mid, gate, 128);
  // GEMM2: out[16384x1024] = mid[16384x768] · W2r[1024x768]^T (+epilogue)
  gemm2p<768, H, 2><<<128 * 4, 512, 49152, stream>>>(
      mid, W2r, x, gate, b2, nullptr, nullptr, out, 128);
}

// Round 7
// 127.267 us; speedup vs baseline: 1.6710x; 1.0422x over previous
//
#include <hip/hip_runtime.h>
#include <cstdint>

#define T_TOK 16384
#define H 1024
#define F 256
#define D 3
#define DF 768

typedef unsigned short u16;
typedef __attribute__((ext_vector_type(8))) short short8;
typedef __attribute__((ext_vector_type(4))) float floatx4;

__device__ __forceinline__ u16 f2bf(float f) {
  unsigned u = __float_as_uint(f);
  u += 0x7fff + ((u >> 16) & 1);   // round-to-nearest-even
  return (u16)(u >> 16);
}
__device__ __forceinline__ float bf2f(u16 s) {
  return __uint_as_float(((unsigned)s) << 16);
}

__device__ __forceinline__ void gload_lds16(const void* g, void* l) {
  __builtin_amdgcn_global_load_lds(
      reinterpret_cast<const __attribute__((address_space(1))) void*>(
          reinterpret_cast<uintptr_t>(g)),
      reinterpret_cast<__attribute__((address_space(3))) void*>(
          reinterpret_cast<uintptr_t>(l)),
      16, 0, 0);
}

__device__ __forceinline__ float block_reduce_256(float v, float* red, int tid) {
  #pragma unroll
  for (int o = 32; o > 0; o >>= 1) v += __shfl_xor(v, o);
  __syncthreads();
  if ((tid & 63) == 0) red[tid >> 6] = v;
  __syncthreads();
  return red[0] + red[1] + red[2] + red[3];
}

// ---------------- prep kernels ----------------

__global__ __launch_bounds__(256)
void prep_elem(const float* __restrict__ W1, const float* __restrict__ lng,
               u16* __restrict__ W1p, const float* __restrict__ W2,
               u16* __restrict__ W2r)
{
  int idx = blockIdx.x * 256 + threadIdx.x;
  int stride = gridDim.x * 256;
  for (int i = idx; i < D * F * H; i += stride) {
    int h = i & (H - 1);
    int d = i / (F * H);
    W1p[i] = f2bf(W1[i] * lng[d * H + h]);
  }
  for (int i = idx; i < H * DF; i += stride) {
    int k = i % DF;           // d*F+f
    int hh = i / DF;
    int d = k >> 8;
    int f = k & (F - 1);
    W2r[i] = f2bf(W2[((size_t)d * H + hh) * F + f]);
  }
}

__global__ __launch_bounds__(256)
void prep_dots(const float* __restrict__ W1, const float* __restrict__ lnb,
               const float* __restrict__ b1, const float* __restrict__ W2,
               const float* __restrict__ gv, const float* __restrict__ b2,
               const float* __restrict__ gb, float* __restrict__ b1p,
               float* __restrict__ wg, float* __restrict__ cg)
{
  __shared__ float red[4];
  int d = blockIdx.x >> 8;
  int f = blockIdx.x & 255;
  int tid = threadIdx.x;
  float s1 = 0.f, s2 = 0.f, s3 = 0.f;
  for (int h = tid; h < H; h += 256) {
    float w1v = W1[((size_t)d * F + f) * H + h];
    float gvv = gv[d * H + h];
    s1 += lnb[d * H + h] * w1v;
    s2 += W2[((size_t)d * H + h) * F + f] * gvv;
    if (f == 0) s3 += b2[d * H + h] * gvv;
  }
  float S1 = block_reduce_256(s1, red, tid);
  float S2 = block_reduce_256(s2, red, tid);
  if (tid == 0) {
    b1p[d * F + f] = b1[d * F + f] + S1;
    wg[d * F + f] = S2;
  }
  if (f == 0) {
    float S3 = block_reduce_256(s3, red, tid);
    if (tid == 0) cg[d] = gb[d] + S3;
  }
}

// ---------------- LayerNorm stats + x·gu dots ----------------
__global__ __launch_bounds__(256)
void ln_xu_kernel(const float* __restrict__ x, const float* __restrict__ gu,
                  u16* __restrict__ xn, float* __restrict__ xu)
{
  int t = blockIdx.x;
  int tid = threadIdx.x;
  const float4 xv = *reinterpret_cast<const float4*>(x + (size_t)t * H + tid * 4);
  const float4 g0 = *reinterpret_cast<const float4*>(gu + tid * 4);
  const float4 g1 = *reinterpret_cast<const float4*>(gu + H + tid * 4);
  const float4 g2 = *reinterpret_cast<const float4*>(gu + 2 * H + tid * 4);
  float s  = xv.x + xv.y + xv.z + xv.w;
  float sq = xv.x * xv.x + xv.y * xv.y + xv.z * xv.z + xv.w * xv.w;
  float d0 = xv.x * g0.x + xv.y * g0.y + xv.z * g0.z + xv.w * g0.w;
  float d1 = xv.x * g1.x + xv.y * g1.y + xv.z * g1.z + xv.w * g1.w;
  float d2 = xv.x * g2.x + xv.y * g2.y + xv.z * g2.z + xv.w * g2.w;
  #pragma unroll
  for (int o = 32; o > 0; o >>= 1) {
    s  += __shfl_xor(s, o);  sq += __shfl_xor(sq, o);
    d0 += __shfl_xor(d0, o); d1 += __shfl_xor(d1, o); d2 += __shfl_xor(d2, o);
  }
  __shared__ float red[4][5];
  int w = tid >> 6;
  if ((tid & 63) == 0) {
    red[w][0] = s; red[w][1] = sq; red[w][2] = d0; red[w][3] = d1; red[w][4] = d2;
  }
  __syncthreads();
  float S  = red[0][0] + red[1][0] + red[2][0] + red[3][0];
  float SQ = red[0][1] + red[1][1] + red[2][1] + red[3][1];
  float mu = S * (1.0f / H);
  float var = (SQ - (float)H * mu * mu) * (1.0f / (H - 1));
  float rs = 1.0f / (sqrtf(fmaxf(var, 0.0f)) + 1e-6f);
  ushort4 o4;
  o4.x = f2bf((xv.x - mu) * rs);
  o4.y = f2bf((xv.y - mu) * rs);
  o4.z = f2bf((xv.z - mu) * rs);
  o4.w = f2bf((xv.w - mu) * rs);
  *reinterpret_cast<ushort4*>(xn + (size_t)t * H + tid * 4) = o4;
  if (tid == 0) {
    xu[t]             = red[0][2] + red[1][2] + red[2][2] + red[3][2];
    xu[T_TOK + t]     = red[0][3] + red[1][3] + red[2][3] + red[3][3];
    xu[2 * T_TOK + t] = red[0][4] + red[1][4] + red[2][4] + red[3][4];
  }
}

// ---------------- 2-phase 128x256xBK32 GEMM: C = A·B^T ----------------
// Loop structure = R6 (best so far): dbuf LDS, one __syncthreads per
// K-tile, compiler-managed waits, chunk-XOR swizzle (2-way banks).
// R7 changes:
//  (1) panel-locality dispatch: xcd=bid&7; within an XCD the nBx blocks
//      sharing one A-panel (same by) are CONSECUTIVE -> A fetched once
//      into that XCD's L2 (fixes measured 2.6x A re-fetch).
//  (2) EPI1 vectorized stores: midg bounced through padded LDS tile
//      (stride 264 u16) then cooperative short8 stores -> full 64B
//      sectors (fixes measured 2.7x write amplification on bf16 out).
template <int K, int NLD, int EPI>
__global__ __launch_bounds__(512, 4)
void gemm2p(const u16* __restrict__ A, const u16* __restrict__ Bm,
            const float* __restrict__ p0,  // EPI1: b1p  EPI2: x
            const float* __restrict__ p1,  // EPI1: wg   EPI2: gate[3][T]
            const float* __restrict__ p2,  // EPI1: xu   EPI2: b2[3][H]
            const float* __restrict__ p3,  // EPI1: cg   EPI2: unused
            u16* __restrict__ o16,         // EPI1: mid
            float* __restrict__ o32,       // EPI1: gateOut  EPI2: out
            int nBx)
{
  constexpr int NT = K / 32;          // K-tiles
  constexpr int BUF = 12288;          // u16 elems per buffer (24KB)
  extern __shared__ u16 LD[];

  const int tid = threadIdx.x, lane = tid & 63, w = tid >> 6;
  const int wm = w >> 2, wn = w & 3, lr = lane & 15, sl = lane >> 4;

  // panel-locality dispatch: 128 by-tiles = 8 XCDs x 16; the nBx blocks
  // of one by-panel are adjacent on one XCD (grid = 128*nBx)
  const int bid = blockIdx.x;
  const int xcd = bid & 7, idx = bid >> 3;
  const int by = xcd * 16 + idx / nBx;
  const int bx = idx % nBx;
  const int m0 = by * 128, n0 = bx * 256;

  const u16* Asrc = A + (size_t)m0 * K;
  const u16* Bsrc = Bm + (size_t)n0 * K;

  // staging: thread -> (row = tid>>2, chunk cs = tid&3), source chunk
  // pre-swizzled: sc = cs ^ ((row>>1)&3) = (tid&3) ^ ((tid>>3)&3)
  const int sc = (tid & 3) ^ ((tid >> 3) & 3);
  const int srcA  = (tid >> 2) * K + sc * 8;       // rows 0..127
  const int srcB1 = srcA + 128 * K;                // B rows 128..255 (same key)
  const int dstA  = w * 512;                       // wave-uniform dest bases
  const int dstB0 = 4096 + w * 512;
  const int dstB1 = 8192 + w * 512;

  // fragment reads: row = {wm,wn}*64 + frag*16 + lr; key = (lr>>1)&3
  const int key = (lr >> 1) & 3;
  const int rsl = (sl ^ key) << 3;
  const int aoff = (wm * 64 + lr) * 32 + rsl;           // A slab @0
  const int boff = 4096 + (wn * 64 + lr) * 32 + rsl;    // B slab @4096

  floatx4 acc[4][4] = {};
  short8 a[4], b[4];

#define STG(BP, T_) do { int kb_ = (T_) * 32; \
    gload_lds16(Asrc + srcA + kb_, (BP) + dstA); \
    gload_lds16(Bsrc + srcA + kb_, (BP) + dstB0); \
    gload_lds16(Bsrc + srcB1 + kb_, (BP) + dstB1); \
  } while (0)
#define LDAB(BP) do { \
    const u16* sa_ = (BP) + aoff; const u16* sb_ = (BP) + boff; \
    _Pragma("unroll") for (int i_ = 0; i_ < 4; ++i_) { \
      a[i_] = *reinterpret_cast<const short8*>(sa_ + i_ * 512); \
      b[i_] = *reinterpret_cast<const short8*>(sb_ + i_ * 512); } } while (0)
#define MMX() do { \
    _Pragma("unroll") for (int mf_ = 0; mf_ < 4; ++mf_) \
      _Pragma("unroll") for (int nf_ = 0; nf_ < 4; ++nf_) \
        acc[mf_][nf_] = __builtin_amdgcn_mfma_f32_16x16x32_bf16( \
            a[mf_], b[nf_], acc[mf_][nf_], 0, 0, 0); } while (0)

  STG(LD, 0);
  __syncthreads();

  #pragma unroll 1
  for (int t = 0; t < NT - 1; ++t) {
    u16* cur = LD + (t & 1) * BUF;
    u16* nxt = LD + ((t + 1) & 1) * BUF;
    STG(nxt, t + 1);          // async; drained by the syncthreads below
    LDAB(cur);
    MMX();
    __syncthreads();          // compiler: waitcnt vmcnt(0) lgkmcnt(0) + barrier
  }
  LDAB(LD + ((NT - 1) & 1) * BUF);
  MMX();
  __syncthreads();            // LDS free for epilogue

  // ---- epilogue; C/D frag layout: col=lane&15, row=(lane>>4)*4+i ----
  if constexpr (EPI == 1) {
    // mid = relu(acc + b1p); fused gate: g = sigmoid(Σ mid·wg + xu + cg);
    // store midg via LDS transpose -> short8 (full-sector writes)
    float b1v[4], wgv[4];
    #pragma unroll
    for (int nf = 0; nf < 4; ++nf) {
      int col = n0 + wn * 64 + nf * 16 + lr;
      b1v[nf] = p0[col];
      wgv[nf] = p1[col];
    }
    float* red = (float*)LD;   // [4 wn][128 rows] (2KB at base)
    #pragma unroll
    for (int mf = 0; mf < 4; ++mf)
      #pragma unroll
      for (int i2 = 0; i2 < 4; ++i2) {
        float p = 0.f;
        #pragma unroll
        for (int nf = 0; nf < 4; ++nf)
          p += fmaxf(acc[mf][nf][i2] + b1v[nf], 0.f) * wgv[nf];
        p += __shfl_xor(p, 1); p += __shfl_xor(p, 2);
        p += __shfl_xor(p, 4); p += __shfl_xor(p, 8);
        if (lr == 0) red[wn * 128 + wm * 64 + mf * 16 + sl * 4 + i2] = p;
      }
    __syncthreads();
    const int d = bx;          // block n-tile == domain
    const float cgv = p3[d];
    float gv_[4][4];
    #pragma unroll
    for (int mf = 0; mf < 4; ++mf)
      #pragma unroll
      for (int i2 = 0; i2 < 4; ++i2) {
        int rl = wm * 64 + mf * 16 + sl * 4 + i2;
        int r = m0 + rl;
        float logit = red[rl] + red[128 + rl] + red[256 + rl] + red[384 + rl]
                    + p2[(size_t)d * T_TOK + r] + cgv;
        float g = 1.f / (1.f + expf(-logit));
        gv_[mf][i2] = g;
        if (lr == 0 && wn == 0) o32[(size_t)d * T_TOK + r] = g;
      }
    __syncthreads();           // everyone done reading red
    // midg -> LDS tile [128][264] u16 (pad 8 breaks sl-group conflicts)
    #pragma unroll
    for (int mf = 0; mf < 4; ++mf)
      #pragma unroll
      for (int i2 = 0; i2 < 4; ++i2) {
        int rl = wm * 64 + mf * 16 + sl * 4 + i2;
        #pragma unroll
        for (int nf = 0; nf < 4; ++nf) {
          int cl = wn * 64 + nf * 16 + lr;
          float v = fmaxf(acc[mf][nf][i2] + b1v[nf], 0.f);
          LD[rl * 264 + cl] = f2bf(v * gv_[mf][i2]);
        }
      }
    __syncthreads();
    // cooperative vector store: 128 rows x 32 chunks of 16B
    #pragma unroll
    for (int ps = 0; ps < 8; ++ps) {
      int q = ps * 512 + tid;
      int row = q >> 5, ch = q & 31;
      short8 v = *reinterpret_cast<const short8*>(LD + row * 264 + ch * 8);
      *reinterpret_cast<short8*>(&o16[(size_t)(m0 + row) * NLD + n0 + ch * 8]) = v;
    }
  } else {
    // out = acc + 2x + Σ_d g_d·b2[d]  (fp32 stores: full sectors already)
    float b2v[3][4];
    #pragma unroll
    for (int dd = 0; dd < 3; ++dd)
      #pragma unroll
      for (int nf = 0; nf < 4; ++nf)
        b2v[dd][nf] = p2[dd * H + n0 + wn * 64 + nf * 16 + lr];
    #pragma unroll
    for (int mf = 0; mf < 4; ++mf)
      #pragma unroll
      for (int i2 = 0; i2 < 4; ++i2) {
        int r = m0 + wm * 64 + mf * 16 + sl * 4 + i2;
        float g0 = p1[r], g1 = p1[T_TOK + r], g2 = p1[2 * T_TOK + r];
        const float* xrow = p0 + (size_t)r * H;
        float* orow = o32 + (size_t)r * NLD;
        #pragma unroll
        for (int nf = 0; nf < 4; ++nf) {
          int col = n0 + wn * 64 + nf * 16 + lr;
          orow[col] = acc[mf][nf][i2] + 2.f * xrow[col]
                    + g0 * b2v[0][nf] + g1 * b2v[1][nf] + g2 * b2v[2][nf];
        }
      }
  }
#undef STG
#undef LDAB
#undef MMX
}

// ---------------- launch ----------------

extern "C" void kernel_launch(void* const* d_in, const int* in_sizes, int n_in,
                              void* d_out, int out_size, void* d_ws, size_t ws_size,
                              hipStream_t stream) {
  const float* x   = (const float*)d_in[0];
  const float* lng = (const float*)d_in[1];
  const float* lnb = (const float*)d_in[2];
  const float* W1  = (const float*)d_in[3];
  const float* b1  = (const float*)d_in[4];
  const float* W2  = (const float*)d_in[5];
  const float* b2  = (const float*)d_in[6];
  const float* gu  = (const float*)d_in[7];
  const float* gv  = (const float*)d_in[8];
  const float* gb  = (const float*)d_in[9];
  float* out = (float*)d_out;

  char* ws = (char*)d_ws;
  u16* xn   = (u16*)ws;  ws += (size_t)T_TOK * H * 2;     // 32 MB
  u16* mid  = (u16*)ws;  ws += (size_t)T_TOK * DF * 2;    // 24 MB
  u16* W1p  = (u16*)ws;  ws += (size_t)DF * H * 2;
  u16* W2r  = (u16*)ws;  ws += (size_t)H * DF * 2;
  float* b1p  = (float*)ws;  ws += DF * 4;
  float* wg   = (float*)ws;  ws += DF * 4;
  float* cg   = (float*)ws;  ws += 256;
  float* xu   = (float*)ws;  ws += (size_t)D * T_TOK * 4;
  float* gate = (float*)ws;  ws += (size_t)D * T_TOK * 4;
  (void)ws_size; (void)in_sizes; (void)n_in; (void)out_size;

  hipFuncSetAttribute(reinterpret_cast<const void*>(&gemm2p<1024, DF, 1>),
                      hipFuncAttributeMaxDynamicSharedMemorySize, 67584);
  hipFuncSetAttribute(reinterpret_cast<const void*>(&gemm2p<768, H, 2>),
                      hipFuncAttributeMaxDynamicSharedMemorySize, 49152);

  prep_elem<<<3072, 256, 0, stream>>>(W1, lng, W1p, W2, W2r);
  prep_dots<<<DF, 256, 0, stream>>>(W1, lnb, b1, W2, gv, b2, gb, b1p, wg, cg);
  ln_xu_kernel<<<T_TOK, 256, 0, stream>>>(x, gu, xn, xu);
  // GEMM1: mid[16384x768] = xn[16384x1024] · W1p[768x1024]^T  (+gate)
  gemm2p<1024, DF, 1><<<128 * 3, 512, 67584, stream>>>(
      xn, W1p, b1p, wg, xu, cg, mid, gate, 3);
  // GEMM2: out[16384x1024] = mid[16384x768] · W2r[1024x768]^T (+epilogue)
  gemm2p<768, H, 2><<<128 * 4, 512, 49152, stream>>>(
      mid, W2r, x, gate, b2, nullptr, nullptr, out, 4);
}